// Round 1
// baseline (983.691 us; speedup 1.0000x reference)
//
#include <hip/hip_runtime.h>
#include <math.h>

#define N_HEADS 4
#define D_IN    128
#define D_OUT   32
#define D_TOT   128   // N_HEADS * D_OUT

// ---------------------------------------------------------------------------
// Kernel 1: per-node projection Wh[n][k][o] = sum_i x[n][i] * W[k][i][o]
// fused with attention row-dots:
//   s_src[n][k] = sum_o Wh[n][k][o] * a[k][o]
//   s_tgt[n][k] = sum_o Wh[n][k][o] * a[k][D_OUT+o]
// One block (128 threads = 2 waves) per node. thread t: k = t>>5, o = t&31.
// ---------------------------------------------------------------------------
__global__ void proj_kernel(const float* __restrict__ x,
                            const float* __restrict__ W,
                            const float* __restrict__ a,
                            float* __restrict__ Wh,
                            float* __restrict__ s_src,
                            float* __restrict__ s_tgt) {
    const int n = blockIdx.x;
    const int t = threadIdx.x;          // 0..127
    const int k = t >> 5;
    const int o = t & 31;

    __shared__ float xs[D_IN];
    xs[t] = x[n * D_IN + t];
    __syncthreads();

    const float* Wk = W + k * (D_IN * D_OUT) + o;   // column o of head k
    float acc = 0.f;
    #pragma unroll
    for (int i = 0; i < D_IN; ++i) {
        acc = fmaf(xs[i], Wk[i * D_OUT], acc);
    }
    Wh[n * D_TOT + t] = acc;

    float vs = acc * a[k * (2 * D_OUT) + o];
    float vt = acc * a[k * (2 * D_OUT) + D_OUT + o];
    // reduce over the 32 lanes sharing head k (width-32 partitions of wave64)
    #pragma unroll
    for (int off = 16; off > 0; off >>= 1) {
        vs += __shfl_down(vs, off, 32);
        vt += __shfl_down(vt, off, 32);
    }
    if (o == 0) {
        s_src[n * N_HEADS + k] = vs;
        s_tgt[n * N_HEADS + k] = vt;
    }
}

// ---------------------------------------------------------------------------
// Kernel 2: per (edge, head): e = LeakyReLU(s_src[src]+s_tgt[tgt]);
// atomic-accumulate exp(e) into e_sum[tgt][k].
// No max-shift needed: |e| ~ O(0.05), exp() is safe; result is mathematically
// identical to the reference's shifted softmax.
// ---------------------------------------------------------------------------
__global__ void edge_sum_kernel(const int* __restrict__ ei,
                                const float* __restrict__ s_src,
                                const float* __restrict__ s_tgt,
                                float* __restrict__ e_sum,
                                int E) {
    int idx = blockIdx.x * blockDim.x + threadIdx.x;
    if (idx >= E * N_HEADS) return;
    int e = idx >> 2;
    int k = idx & 3;
    int src = ei[e];
    int tgt = ei[E + e];
    float v = s_src[src * N_HEADS + k] + s_tgt[tgt * N_HEADS + k];
    v = v > 0.f ? v : 0.2f * v;
    atomicAdd(&e_sum[tgt * N_HEADS + k], expf(v));
}

// ---------------------------------------------------------------------------
// Kernel 3: per (edge, feature): alpha = exp(e)/ (e_sum[tgt]+1e-10);
// atomicAdd alpha * Wh[src][f] into out[tgt][f].
// ---------------------------------------------------------------------------
__global__ void aggregate_kernel(const int* __restrict__ ei,
                                 const float* __restrict__ s_src,
                                 const float* __restrict__ s_tgt,
                                 const float* __restrict__ e_sum,
                                 const float* __restrict__ Wh,
                                 float* __restrict__ out,
                                 int E) {
    int idx = blockIdx.x * blockDim.x + threadIdx.x;   // < E*128 = 204.8M < 2^31
    if (idx >= E * D_TOT) return;
    int e = idx >> 7;          // edge id
    int f = idx & 127;         // feature id (k*32+o)
    int k = f >> 5;
    int src = ei[e];
    int tgt = ei[E + e];
    float v = s_src[src * N_HEADS + k] + s_tgt[tgt * N_HEADS + k];
    v = v > 0.f ? v : 0.2f * v;
    float alpha = expf(v) / (e_sum[tgt * N_HEADS + k] + 1e-10f);
    atomicAdd(&out[tgt * D_TOT + f], alpha * Wh[src * D_TOT + f]);
}

// ---------------------------------------------------------------------------
// Kernel 4: ELU epilogue on out.
// ---------------------------------------------------------------------------
__global__ void elu_kernel(float* __restrict__ out, int n) {
    int idx = blockIdx.x * blockDim.x + threadIdx.x;
    if (idx >= n) return;
    float v = out[idx];
    out[idx] = v > 0.f ? v : expm1f(v);
}

extern "C" void kernel_launch(void* const* d_in, const int* in_sizes, int n_in,
                              void* d_out, int out_size, void* d_ws, size_t ws_size,
                              hipStream_t stream) {
    const float* x  = (const float*)d_in[0];
    const int*   ei = (const int*)d_in[1];
    const float* W  = (const float*)d_in[2];
    const float* a  = (const float*)d_in[3];
    float* out = (float*)d_out;

    const int N = in_sizes[0] / D_IN;   // 50000
    const int E = in_sizes[1] / 2;      // 1600000

    // workspace layout (floats): Wh[N*128] | s_src[N*4] | s_tgt[N*4] | e_sum[N*4]
    float* Wh    = (float*)d_ws;
    float* s_src = Wh    + (size_t)N * D_TOT;
    float* s_tgt = s_src + (size_t)N * N_HEADS;
    float* e_sum = s_tgt + (size_t)N * N_HEADS;

    // zero the accumulators (ws/out are poisoned 0xAA before every launch)
    hipMemsetAsync(e_sum, 0, (size_t)N * N_HEADS * sizeof(float), stream);
    hipMemsetAsync(out,   0, (size_t)N * D_TOT  * sizeof(float), stream);

    proj_kernel<<<N, D_TOT, 0, stream>>>(x, W, a, Wh, s_src, s_tgt);

    {
        int tot = E * N_HEADS;
        edge_sum_kernel<<<(tot + 255) / 256, 256, 0, stream>>>(ei, s_src, s_tgt, e_sum, E);
    }
    {
        long long tot = (long long)E * D_TOT;   // 204.8M
        aggregate_kernel<<<(int)((tot + 255) / 256), 256, 0, stream>>>(
            ei, s_src, s_tgt, e_sum, Wh, out, E);
    }
    {
        int tot = N * D_TOT;
        elu_kernel<<<(tot + 255) / 256, 256, 0, stream>>>(out, tot);
    }
}

// Round 2
// 510.525 us; speedup vs baseline: 1.9268x; 1.9268x over previous
//
#include <hip/hip_runtime.h>
#include <math.h>

#define N_HEADS 4
#define D_IN    128
#define D_OUT   32
#define D_TOT   128   // N_HEADS * D_OUT

// ---------------------------------------------------------------------------
// Kernel 1: per-node projection Wh[n][k][o] = sum_i x[n][i] * W[k][i][o]
// fused with attention row-dots s_src / s_tgt.
// One block (128 threads = 2 waves) per node. thread t: k = t>>5, o = t&31.
// ---------------------------------------------------------------------------
__global__ void proj_kernel(const float* __restrict__ x,
                            const float* __restrict__ W,
                            const float* __restrict__ a,
                            float* __restrict__ Wh,
                            float* __restrict__ s_src,
                            float* __restrict__ s_tgt) {
    const int n = blockIdx.x;
    const int t = threadIdx.x;          // 0..127
    const int k = t >> 5;
    const int o = t & 31;

    __shared__ float xs[D_IN];
    xs[t] = x[n * D_IN + t];
    __syncthreads();

    const float* Wk = W + k * (D_IN * D_OUT) + o;   // column o of head k
    float acc = 0.f;
    #pragma unroll
    for (int i = 0; i < D_IN; ++i) {
        acc = fmaf(xs[i], Wk[i * D_OUT], acc);
    }
    Wh[n * D_TOT + t] = acc;

    float vs = acc * a[k * (2 * D_OUT) + o];
    float vt = acc * a[k * (2 * D_OUT) + D_OUT + o];
    #pragma unroll
    for (int off = 16; off > 0; off >>= 1) {
        vs += __shfl_down(vs, off, 32);
        vt += __shfl_down(vt, off, 32);
    }
    if (o == 0) {
        s_src[n * N_HEADS + k] = vs;
        s_tgt[n * N_HEADS + k] = vt;
    }
}

// ---------------------------------------------------------------------------
// CSR build: degree count -> exclusive scan -> bucket scatter of src ids.
// ---------------------------------------------------------------------------
__global__ void degree_kernel(const int* __restrict__ ei, int* __restrict__ deg, int E) {
    int e = blockIdx.x * blockDim.x + threadIdx.x;
    if (e < E) atomicAdd(&deg[ei[E + e]], 1);   // tgt row
}

// Single-block exclusive scan over N elements -> row_start[0..N].
__global__ __launch_bounds__(1024) void scan_kernel(const int* __restrict__ deg,
                                                    int* __restrict__ row_start, int N) {
    __shared__ int wsum[16];
    __shared__ int woff[16];
    __shared__ int carry_s;
    __shared__ int wtot_s;
    const int lane = threadIdx.x & 63;
    const int wid  = threadIdx.x >> 6;
    if (threadIdx.x == 0) { carry_s = 0; row_start[0] = 0; }
    __syncthreads();
    for (int base = 0; base < N; base += 1024) {
        int i = base + threadIdx.x;
        int v = (i < N) ? deg[i] : 0;
        int incl = v;
        #pragma unroll
        for (int off = 1; off < 64; off <<= 1) {
            int tv = __shfl_up(incl, off, 64);
            if (lane >= off) incl += tv;
        }
        if (lane == 63) wsum[wid] = incl;
        __syncthreads();
        if (threadIdx.x == 0) {
            int c = 0;
            #pragma unroll
            for (int w = 0; w < 16; ++w) { woff[w] = c; c += wsum[w]; }
            wtot_s = c;
        }
        __syncthreads();
        if (i < N) row_start[i + 1] = carry_s + woff[wid] + incl;
        __syncthreads();
        if (threadIdx.x == 0) carry_s += wtot_s;
        __syncthreads();
    }
}

__global__ void scatter_kernel(const int* __restrict__ ei,
                               const int* __restrict__ row_start,
                               int* __restrict__ cursor,
                               int* __restrict__ rec, int E) {
    int e = blockIdx.x * blockDim.x + threadIdx.x;
    if (e >= E) return;
    int src = ei[e];
    int tgt = ei[E + e];
    int pos = atomicAdd(&cursor[tgt], 1);
    rec[row_start[tgt] + pos] = src;
}

// ---------------------------------------------------------------------------
// Aggregate: one block (64 threads = 1 wave) per target node. Each thread owns
// a float2 feature pair. Walk incoming edges, accumulate num += ev*Wh[src],
// den += ev in registers; out = ELU(num/(den+1e-10)). No atomics, one write.
// ---------------------------------------------------------------------------
__global__ __launch_bounds__(64) void agg_kernel(const int* __restrict__ rec,
                                                 const int* __restrict__ row_start,
                                                 const float* __restrict__ s_src,
                                                 const float* __restrict__ s_tgt,
                                                 const float* __restrict__ Wh,
                                                 float* __restrict__ out) {
    const int n = blockIdx.x;
    const int t = threadIdx.x;        // 0..63
    const int f = t * 2;              // feature pair base
    const int k = f >> 5;             // head (pair never straddles heads)
    const int beg = row_start[n];
    const int end = row_start[n + 1];
    const float stk = s_tgt[n * N_HEADS + k];
    const float2* __restrict__ Wh2 = (const float2*)Wh;

    float den = 0.f;
    float nx = 0.f, ny = 0.f;
    int j = beg;
    for (; j + 4 <= end; j += 4) {
        int s0 = rec[j], s1 = rec[j + 1], s2 = rec[j + 2], s3 = rec[j + 3];
        float a0 = s_src[s0 * N_HEADS + k] + stk;
        float a1 = s_src[s1 * N_HEADS + k] + stk;
        float a2 = s_src[s2 * N_HEADS + k] + stk;
        float a3 = s_src[s3 * N_HEADS + k] + stk;
        float2 w0 = Wh2[(size_t)s0 * 64 + t];
        float2 w1 = Wh2[(size_t)s1 * 64 + t];
        float2 w2 = Wh2[(size_t)s2 * 64 + t];
        float2 w3 = Wh2[(size_t)s3 * 64 + t];
        a0 = a0 > 0.f ? a0 : 0.2f * a0;
        a1 = a1 > 0.f ? a1 : 0.2f * a1;
        a2 = a2 > 0.f ? a2 : 0.2f * a2;
        a3 = a3 > 0.f ? a3 : 0.2f * a3;
        float e0 = __expf(a0), e1 = __expf(a1), e2 = __expf(a2), e3 = __expf(a3);
        den += (e0 + e1) + (e2 + e3);
        nx = fmaf(e0, w0.x, nx); ny = fmaf(e0, w0.y, ny);
        nx = fmaf(e1, w1.x, nx); ny = fmaf(e1, w1.y, ny);
        nx = fmaf(e2, w2.x, nx); ny = fmaf(e2, w2.y, ny);
        nx = fmaf(e3, w3.x, nx); ny = fmaf(e3, w3.y, ny);
    }
    for (; j < end; ++j) {
        int s0 = rec[j];
        float a0 = s_src[s0 * N_HEADS + k] + stk;
        float2 w0 = Wh2[(size_t)s0 * 64 + t];
        a0 = a0 > 0.f ? a0 : 0.2f * a0;
        float e0 = __expf(a0);
        den += e0;
        nx = fmaf(e0, w0.x, nx); ny = fmaf(e0, w0.y, ny);
    }
    float inv = 1.f / (den + 1e-10f);
    float ox = nx * inv, oy = ny * inv;
    out[n * D_TOT + f]     = ox > 0.f ? ox : expm1f(ox);
    out[n * D_TOT + f + 1] = oy > 0.f ? oy : expm1f(oy);
}

extern "C" void kernel_launch(void* const* d_in, const int* in_sizes, int n_in,
                              void* d_out, int out_size, void* d_ws, size_t ws_size,
                              hipStream_t stream) {
    const float* x  = (const float*)d_in[0];
    const int*   ei = (const int*)d_in[1];
    const float* W  = (const float*)d_in[2];
    const float* a  = (const float*)d_in[3];
    float* out = (float*)d_out;

    const int N = in_sizes[0] / D_IN;   // 50000
    const int E = in_sizes[1] / 2;      // 1600000

    // workspace layout:
    // Wh[N*128] f32 | s_src[N*4] | s_tgt[N*4] | deg[N] i32 | row_start[N+1] | cursor[N] | rec[E]
    float* Wh       = (float*)d_ws;
    float* s_src    = Wh + (size_t)N * D_TOT;
    float* s_tgt    = s_src + (size_t)N * N_HEADS;
    int*   deg      = (int*)(s_tgt + (size_t)N * N_HEADS);
    int*   rowstart = deg + N;
    int*   cursor   = rowstart + N + 1;
    int*   rec      = cursor + N;

    hipMemsetAsync(deg,    0, (size_t)N * sizeof(int), stream);
    hipMemsetAsync(cursor, 0, (size_t)N * sizeof(int), stream);

    proj_kernel<<<N, D_TOT, 0, stream>>>(x, W, a, Wh, s_src, s_tgt);
    degree_kernel<<<(E + 255) / 256, 256, 0, stream>>>(ei, deg, E);
    scan_kernel<<<1, 1024, 0, stream>>>(deg, rowstart, N);
    scatter_kernel<<<(E + 255) / 256, 256, 0, stream>>>(ei, rowstart, cursor, rec, E);
    agg_kernel<<<N, 64, 0, stream>>>(rec, rowstart, s_src, s_tgt, Wh, out);
}

// Round 3
// 402.995 us; speedup vs baseline: 2.4410x; 1.2668x over previous
//
#include <hip/hip_runtime.h>
#include <math.h>

#define N_HEADS 4
#define D_IN    128
#define D_OUT   32
#define D_TOT   128   // N_HEADS * D_OUT
#define NPB     16    // nodes per proj block

// ---------------------------------------------------------------------------
// Fused kernel: proj (+ s_src/s_tgt row-dots) on blocks [0, nProj),
// degree count on blocks [nProj, gridDim). The two parts touch disjoint data
// and overlap on the machine instead of serializing as two dispatches.
//
// proj part: one block = 256 threads = 16 nodes. x-tile staged in LDS
// node-major (broadcast reads, conflict-free). Thread t: feature f = t&127,
// node-group half = t>>7; 8 accumulators -> ILP 8 instead of 1.
// ---------------------------------------------------------------------------
__global__ __launch_bounds__(256) void proj_deg_kernel(
    const float* __restrict__ x,
    const float* __restrict__ W,
    const float* __restrict__ a,
    const int*  __restrict__ ei,
    int*  __restrict__ deg,
    float* __restrict__ Wh,
    float* __restrict__ s_src,
    float* __restrict__ s_tgt,
    int E, int nProj) {

    if (blockIdx.x >= nProj) {
        // ---- degree part: count incoming edges per target node ----
        int nThreads = (gridDim.x - nProj) * 256;
        int start = (blockIdx.x - nProj) * 256 + threadIdx.x;
        for (int e = start; e < E; e += nThreads)
            atomicAdd(&deg[ei[E + e]], 1);
        return;
    }

    __shared__ float xs[NPB][D_IN];
    const int n0 = blockIdx.x * NPB;
    const int t  = threadIdx.x;

    // stage x tile: thread t loads 8 floats of node (t>>4), cols (t&15)*8
    {
        const int nl = t >> 4;
        const int c0 = (t & 15) * 8;
        const float4* src = (const float4*)(x + (size_t)(n0 + nl) * D_IN + c0);
        float4 v0 = src[0];
        float4 v1 = src[1];
        *(float4*)&xs[nl][c0]     = v0;
        *(float4*)&xs[nl][c0 + 4] = v1;
    }
    __syncthreads();

    const int f    = t & 127;
    const int half = t >> 7;          // 0: nodes 0..7, 1: nodes 8..15
    const int k    = f >> 5;
    const int o    = f & 31;
    const float* Wf = W + k * (D_IN * D_OUT) + o;

    float acc[8] = {0.f, 0.f, 0.f, 0.f, 0.f, 0.f, 0.f, 0.f};

    #pragma unroll 4
    for (int i = 0; i < D_IN; i += 4) {
        const float w0 = Wf[(i + 0) * D_OUT];
        const float w1 = Wf[(i + 1) * D_OUT];
        const float w2 = Wf[(i + 2) * D_OUT];
        const float w3 = Wf[(i + 3) * D_OUT];
        #pragma unroll
        for (int nl = 0; nl < 8; ++nl) {
            const float4 xv = *(const float4*)&xs[half * 8 + nl][i];
            acc[nl] = fmaf(xv.x, w0, acc[nl]);
            acc[nl] = fmaf(xv.y, w1, acc[nl]);
            acc[nl] = fmaf(xv.z, w2, acc[nl]);
            acc[nl] = fmaf(xv.w, w3, acc[nl]);
        }
    }

    const float as = a[k * (2 * D_OUT) + o];
    const float at = a[k * (2 * D_OUT) + D_OUT + o];

    #pragma unroll
    for (int nl = 0; nl < 8; ++nl) {
        const int n = n0 + half * 8 + nl;
        Wh[(size_t)n * D_TOT + f] = acc[nl];
        float vs = acc[nl] * as;
        float vt = acc[nl] * at;
        #pragma unroll
        for (int off = 16; off > 0; off >>= 1) {
            vs += __shfl_down(vs, off, 32);
            vt += __shfl_down(vt, off, 32);
        }
        if (o == 0) {
            s_src[n * N_HEADS + k] = vs;
            s_tgt[n * N_HEADS + k] = vt;
        }
    }
}

// ---------------------------------------------------------------------------
// Single-block exclusive scan, 4 elements/thread (int4), -> row_start[0..N].
// ---------------------------------------------------------------------------
__global__ __launch_bounds__(1024) void scan_kernel(const int* __restrict__ deg,
                                                    int* __restrict__ row_start, int N) {
    __shared__ int wsum[16];
    __shared__ int woff[16];
    __shared__ int carry_s;
    __shared__ int wtot_s;
    const int lane = threadIdx.x & 63;
    const int wid  = threadIdx.x >> 6;
    if (threadIdx.x == 0) { carry_s = 0; row_start[0] = 0; }
    __syncthreads();
    for (int base = 0; base < N; base += 4096) {
        const int i0 = base + threadIdx.x * 4;
        int v0 = 0, v1 = 0, v2 = 0, v3 = 0;
        if (i0 + 3 < N) {
            int4 v = *(const int4*)&deg[i0];
            v0 = v.x; v1 = v.y; v2 = v.z; v3 = v.w;
        } else {
            if (i0     < N) v0 = deg[i0];
            if (i0 + 1 < N) v1 = deg[i0 + 1];
            if (i0 + 2 < N) v2 = deg[i0 + 2];
            if (i0 + 3 < N) v3 = deg[i0 + 3];
        }
        const int p0 = v0, p1 = p0 + v1, p2 = p1 + v2, p3 = p2 + v3;
        int incl = p3;
        #pragma unroll
        for (int off = 1; off < 64; off <<= 1) {
            int tv = __shfl_up(incl, off, 64);
            if (lane >= off) incl += tv;
        }
        if (lane == 63) wsum[wid] = incl;
        __syncthreads();
        if (threadIdx.x == 0) {
            int c = 0;
            #pragma unroll
            for (int w = 0; w < 16; ++w) { woff[w] = c; c += wsum[w]; }
            wtot_s = c;
        }
        __syncthreads();
        const int excl = carry_s + woff[wid] + (incl - p3);
        if (i0     < N) row_start[i0 + 1] = excl + p0;
        if (i0 + 1 < N) row_start[i0 + 2] = excl + p1;
        if (i0 + 2 < N) row_start[i0 + 3] = excl + p2;
        if (i0 + 3 < N) row_start[i0 + 4] = excl + p3;
        __syncthreads();
        if (threadIdx.x == 0) carry_s += wtot_s;
        __syncthreads();
    }
}

__global__ void scatter_kernel(const int* __restrict__ ei,
                               const int* __restrict__ row_start,
                               int* __restrict__ cursor,
                               int* __restrict__ rec, int E) {
    int e = blockIdx.x * blockDim.x + threadIdx.x;
    if (e >= E) return;
    int src = ei[e];
    int tgt = ei[E + e];
    int pos = atomicAdd(&cursor[tgt], 1);
    rec[row_start[tgt] + pos] = src;
}

// ---------------------------------------------------------------------------
// Aggregate: one wave per target node, float2 per thread, register softmax
// accumulation, single write with ELU fused. (unchanged from R2)
// ---------------------------------------------------------------------------
__global__ __launch_bounds__(64) void agg_kernel(const int* __restrict__ rec,
                                                 const int* __restrict__ row_start,
                                                 const float* __restrict__ s_src,
                                                 const float* __restrict__ s_tgt,
                                                 const float* __restrict__ Wh,
                                                 float* __restrict__ out) {
    const int n = blockIdx.x;
    const int t = threadIdx.x;        // 0..63
    const int f = t * 2;
    const int k = f >> 5;
    const int beg = row_start[n];
    const int end = row_start[n + 1];
    const float stk = s_tgt[n * N_HEADS + k];
    const float2* __restrict__ Wh2 = (const float2*)Wh;

    float den = 0.f;
    float nx = 0.f, ny = 0.f;
    int j = beg;
    for (; j + 4 <= end; j += 4) {
        int s0 = rec[j], s1 = rec[j + 1], s2 = rec[j + 2], s3 = rec[j + 3];
        float a0 = s_src[s0 * N_HEADS + k] + stk;
        float a1 = s_src[s1 * N_HEADS + k] + stk;
        float a2 = s_src[s2 * N_HEADS + k] + stk;
        float a3 = s_src[s3 * N_HEADS + k] + stk;
        float2 w0 = Wh2[(size_t)s0 * 64 + t];
        float2 w1 = Wh2[(size_t)s1 * 64 + t];
        float2 w2 = Wh2[(size_t)s2 * 64 + t];
        float2 w3 = Wh2[(size_t)s3 * 64 + t];
        a0 = a0 > 0.f ? a0 : 0.2f * a0;
        a1 = a1 > 0.f ? a1 : 0.2f * a1;
        a2 = a2 > 0.f ? a2 : 0.2f * a2;
        a3 = a3 > 0.f ? a3 : 0.2f * a3;
        float e0 = __expf(a0), e1 = __expf(a1), e2 = __expf(a2), e3 = __expf(a3);
        den += (e0 + e1) + (e2 + e3);
        nx = fmaf(e0, w0.x, nx); ny = fmaf(e0, w0.y, ny);
        nx = fmaf(e1, w1.x, nx); ny = fmaf(e1, w1.y, ny);
        nx = fmaf(e2, w2.x, nx); ny = fmaf(e2, w2.y, ny);
        nx = fmaf(e3, w3.x, nx); ny = fmaf(e3, w3.y, ny);
    }
    for (; j < end; ++j) {
        int s0 = rec[j];
        float a0 = s_src[s0 * N_HEADS + k] + stk;
        float2 w0 = Wh2[(size_t)s0 * 64 + t];
        a0 = a0 > 0.f ? a0 : 0.2f * a0;
        float e0 = __expf(a0);
        den += e0;
        nx = fmaf(e0, w0.x, nx); ny = fmaf(e0, w0.y, ny);
    }
    float inv = 1.f / (den + 1e-10f);
    float ox = nx * inv, oy = ny * inv;
    out[n * D_TOT + f]     = ox > 0.f ? ox : expm1f(ox);
    out[n * D_TOT + f + 1] = oy > 0.f ? oy : expm1f(oy);
}

extern "C" void kernel_launch(void* const* d_in, const int* in_sizes, int n_in,
                              void* d_out, int out_size, void* d_ws, size_t ws_size,
                              hipStream_t stream) {
    const float* x  = (const float*)d_in[0];
    const int*   ei = (const int*)d_in[1];
    const float* W  = (const float*)d_in[2];
    const float* a  = (const float*)d_in[3];
    float* out = (float*)d_out;

    const int N = in_sizes[0] / D_IN;   // 50000
    const int E = in_sizes[1] / 2;      // 1600000

    // workspace layout:
    // Wh[N*128] f32 | s_src[N*4] | s_tgt[N*4] | deg[N] i32 | row_start[N+1] | cursor[N] | rec[E]
    float* Wh       = (float*)d_ws;
    float* s_src    = Wh + (size_t)N * D_TOT;
    float* s_tgt    = s_src + (size_t)N * N_HEADS;
    int*   deg      = (int*)(s_tgt + (size_t)N * N_HEADS);
    int*   rowstart = deg + N;
    int*   cursor   = rowstart + N + 1;
    int*   rec      = cursor + N;

    hipMemsetAsync(deg,    0, (size_t)N * sizeof(int), stream);
    hipMemsetAsync(cursor, 0, (size_t)N * sizeof(int), stream);

    const int nProj = N / NPB;          // 3125
    const int nDeg  = 1250;
    proj_deg_kernel<<<nProj + nDeg, 256, 0, stream>>>(
        x, W, a, ei, deg, Wh, s_src, s_tgt, E, nProj);

    scan_kernel<<<1, 1024, 0, stream>>>(deg, rowstart, N);
    scatter_kernel<<<(E + 255) / 256, 256, 0, stream>>>(ei, rowstart, cursor, rec, E);
    agg_kernel<<<N, 64, 0, stream>>>(rec, rowstart, s_src, s_tgt, Wh, out);
}

// Round 4
// 368.811 us; speedup vs baseline: 2.6672x; 1.0927x over previous
//
#include <hip/hip_runtime.h>
#include <math.h>

#define N_HEADS 4
#define D_IN    128
#define D_OUT   32
#define D_TOT   128   // N_HEADS * D_OUT
#define TN      64    // nodes per proj block
#define XPAD    132   // padded LDS row stride (floats): +4 keeps 16B align, breaks bank aliasing

static __device__ __forceinline__ unsigned short f2bf(float f) {
    // round-to-nearest-even f32 -> bf16
    unsigned u = __float_as_uint(f);
    u += 0x7fffu + ((u >> 16) & 1u);
    return (unsigned short)(u >> 16);
}

// ---------------------------------------------------------------------------
// Fused: proj (+ row-dots, bf16 Wh store) on blocks [0,nProj); degree count on
// the rest. proj: 256 threads = 64 nodes x 128 feats tile. Thread t:
// fg = t&15 (8 feats), ng = t>>4 (4 nodes) -> 32 accumulators, so each
// ds_read_b128 of x feeds 32 FMAs/lane (LDS demand = half peak; VALU-bound).
// ---------------------------------------------------------------------------
__global__ __launch_bounds__(256) void proj_deg_kernel(
    const float* __restrict__ x,
    const float* __restrict__ W,
    const float* __restrict__ a,
    const int*  __restrict__ ei,
    int*  __restrict__ deg,
    unsigned int* __restrict__ Whu,   // N x 64 uints (2 bf16 each)
    float* __restrict__ s_src,
    float* __restrict__ s_tgt,
    int N, int E, int nProj) {

    if (blockIdx.x >= nProj) {
        int nThreads = (gridDim.x - nProj) * 256;
        int start = (blockIdx.x - nProj) * 256 + threadIdx.x;
        for (int e = start; e < E; e += nThreads)
            atomicAdd(&deg[ei[E + e]], 1);
        return;
    }

    __shared__ float xs[TN][XPAD];
    const int n0 = blockIdx.x * TN;
    const int t  = threadIdx.x;

    // stage x tile: thread -> row r = t>>2, cols (t&3)*32 .. +31 (8 float4)
    {
        const int r  = t >> 2;
        const int c0 = (t & 3) * 32;
        int nn = n0 + r; if (nn >= N) nn = N - 1;   // tail: duplicate last row
        const float4* src = (const float4*)(x + (size_t)nn * D_IN + c0);
        #pragma unroll
        for (int j = 0; j < 8; ++j)
            *(float4*)&xs[r][c0 + j * 4] = src[j];
    }
    __syncthreads();

    const int fg = t & 15;       // feature group: feats f0..f0+7
    const int ng = t >> 4;       // node group: nodes ng*4..ng*4+3
    const int f0 = fg * 8;
    const int k  = f0 >> 5;      // head (8-feat chunk never straddles heads)
    const int o0 = f0 & 31;
    const float* Wf = W + k * (D_IN * D_OUT) + o0;

    float acc[4][8];
    #pragma unroll
    for (int nl = 0; nl < 4; ++nl)
        #pragma unroll
        for (int j = 0; j < 8; ++j) acc[nl][j] = 0.f;

    #pragma unroll 2
    for (int i = 0; i < D_IN; i += 4) {
        float4 wa[4], wb[4];
        #pragma unroll
        for (int ii = 0; ii < 4; ++ii) {
            wa[ii] = *(const float4*)(Wf + (i + ii) * D_OUT);
            wb[ii] = *(const float4*)(Wf + (i + ii) * D_OUT + 4);
        }
        #pragma unroll
        for (int nl = 0; nl < 4; ++nl) {
            const float4 xv = *(const float4*)&xs[ng * 4 + nl][i];
            const float xr[4] = {xv.x, xv.y, xv.z, xv.w};
            #pragma unroll
            for (int ii = 0; ii < 4; ++ii) {
                acc[nl][0] = fmaf(xr[ii], wa[ii].x, acc[nl][0]);
                acc[nl][1] = fmaf(xr[ii], wa[ii].y, acc[nl][1]);
                acc[nl][2] = fmaf(xr[ii], wa[ii].z, acc[nl][2]);
                acc[nl][3] = fmaf(xr[ii], wa[ii].w, acc[nl][3]);
                acc[nl][4] = fmaf(xr[ii], wb[ii].x, acc[nl][4]);
                acc[nl][5] = fmaf(xr[ii], wb[ii].y, acc[nl][5]);
                acc[nl][6] = fmaf(xr[ii], wb[ii].z, acc[nl][6]);
                acc[nl][7] = fmaf(xr[ii], wb[ii].w, acc[nl][7]);
            }
        }
    }

    const float4 as0 = *(const float4*)(a + k * (2 * D_OUT) + o0);
    const float4 as1 = *(const float4*)(a + k * (2 * D_OUT) + o0 + 4);
    const float4 at0 = *(const float4*)(a + k * (2 * D_OUT) + D_OUT + o0);
    const float4 at1 = *(const float4*)(a + k * (2 * D_OUT) + D_OUT + o0 + 4);

    #pragma unroll
    for (int nl = 0; nl < 4; ++nl) {
        const int n = n0 + ng * 4 + nl;   // uniform within each lane-quad
        if (n < N) {
            unsigned int p[4];
            #pragma unroll
            for (int j = 0; j < 4; ++j)
                p[j] = (unsigned)f2bf(acc[nl][2 * j]) |
                       ((unsigned)f2bf(acc[nl][2 * j + 1]) << 16);
            *(uint4*)&Whu[(size_t)n * 64 + fg * 4] = make_uint4(p[0], p[1], p[2], p[3]);

            float vs = acc[nl][0] * as0.x + acc[nl][1] * as0.y +
                       acc[nl][2] * as0.z + acc[nl][3] * as0.w +
                       acc[nl][4] * as1.x + acc[nl][5] * as1.y +
                       acc[nl][6] * as1.z + acc[nl][7] * as1.w;
            float vt = acc[nl][0] * at0.x + acc[nl][1] * at0.y +
                       acc[nl][2] * at0.z + acc[nl][3] * at0.w +
                       acc[nl][4] * at1.x + acc[nl][5] * at1.y +
                       acc[nl][6] * at1.z + acc[nl][7] * at1.w;
            vs += __shfl_xor(vs, 1, 64); vs += __shfl_xor(vs, 2, 64);
            vt += __shfl_xor(vt, 1, 64); vt += __shfl_xor(vt, 2, 64);
            if ((fg & 3) == 0) {
                s_src[n * N_HEADS + k] = vs;
                s_tgt[n * N_HEADS + k] = vt;
            }
        }
    }
}

// ---------------------------------------------------------------------------
// Single-block exclusive scan (int4/thread). Writes row_start[0..N] AND
// cursor[i] = row_start[i] (scatter consumes cursor directly).
// ---------------------------------------------------------------------------
__global__ __launch_bounds__(1024) void scan_kernel(const int* __restrict__ deg,
                                                    int* __restrict__ row_start,
                                                    int* __restrict__ cursor, int N) {
    __shared__ int wsum[16];
    __shared__ int woff[16];
    __shared__ int carry_s;
    __shared__ int wtot_s;
    const int lane = threadIdx.x & 63;
    const int wid  = threadIdx.x >> 6;
    if (threadIdx.x == 0) { carry_s = 0; row_start[0] = 0; }
    __syncthreads();
    for (int base = 0; base < N; base += 4096) {
        const int i0 = base + threadIdx.x * 4;
        int v0 = 0, v1 = 0, v2 = 0, v3 = 0;
        if (i0 + 3 < N) {
            int4 v = *(const int4*)&deg[i0];
            v0 = v.x; v1 = v.y; v2 = v.z; v3 = v.w;
        } else {
            if (i0     < N) v0 = deg[i0];
            if (i0 + 1 < N) v1 = deg[i0 + 1];
            if (i0 + 2 < N) v2 = deg[i0 + 2];
            if (i0 + 3 < N) v3 = deg[i0 + 3];
        }
        const int p0 = v0, p1 = p0 + v1, p2 = p1 + v2, p3 = p2 + v3;
        int incl = p3;
        #pragma unroll
        for (int off = 1; off < 64; off <<= 1) {
            int tv = __shfl_up(incl, off, 64);
            if (lane >= off) incl += tv;
        }
        if (lane == 63) wsum[wid] = incl;
        __syncthreads();
        if (threadIdx.x == 0) {
            int c = 0;
            #pragma unroll
            for (int w = 0; w < 16; ++w) { woff[w] = c; c += wsum[w]; }
            wtot_s = c;
        }
        __syncthreads();
        const int excl = carry_s + woff[wid] + (incl - p3);
        if (i0     < N) { row_start[i0 + 1] = excl + p0; cursor[i0]     = excl;      }
        if (i0 + 1 < N) { row_start[i0 + 2] = excl + p1; cursor[i0 + 1] = excl + p0; }
        if (i0 + 2 < N) { row_start[i0 + 3] = excl + p2; cursor[i0 + 2] = excl + p1; }
        if (i0 + 3 < N) { row_start[i0 + 4] = excl + p3; cursor[i0 + 3] = excl + p2; }
        __syncthreads();
        if (threadIdx.x == 0) carry_s += wtot_s;
        __syncthreads();
    }
}

__global__ void scatter_kernel(const int* __restrict__ ei,
                               int* __restrict__ cursor,
                               int* __restrict__ rec, int E) {
    int e = blockIdx.x * blockDim.x + threadIdx.x;
    if (e >= E) return;
    int src = ei[e];
    int tgt = ei[E + e];
    int pos = atomicAdd(&cursor[tgt], 1);
    rec[pos] = src;
}

// ---------------------------------------------------------------------------
// Aggregate: one wave per target node; thread t owns feats {2t,2t+1} read as
// one packed-bf16 uint (256B/edge gather). Register softmax accumulation,
// single f32 write with ELU fused.
// ---------------------------------------------------------------------------
__global__ __launch_bounds__(64) void agg_kernel(const int* __restrict__ rec,
                                                 const int* __restrict__ row_start,
                                                 const float* __restrict__ s_src,
                                                 const float* __restrict__ s_tgt,
                                                 const unsigned int* __restrict__ Whu,
                                                 float* __restrict__ out) {
    const int n = blockIdx.x;
    const int t = threadIdx.x;        // 0..63
    const int f = t * 2;
    const int k = f >> 5;
    const int beg = row_start[n];
    const int end = row_start[n + 1];
    const float stk = s_tgt[n * N_HEADS + k];

    float den = 0.f;
    float nx = 0.f, ny = 0.f;
    int j = beg;
    for (; j + 4 <= end; j += 4) {
        int s0 = rec[j], s1 = rec[j + 1], s2 = rec[j + 2], s3 = rec[j + 3];
        float a0 = s_src[s0 * N_HEADS + k] + stk;
        float a1 = s_src[s1 * N_HEADS + k] + stk;
        float a2 = s_src[s2 * N_HEADS + k] + stk;
        float a3 = s_src[s3 * N_HEADS + k] + stk;
        unsigned w0 = Whu[(size_t)s0 * 64 + t];
        unsigned w1 = Whu[(size_t)s1 * 64 + t];
        unsigned w2 = Whu[(size_t)s2 * 64 + t];
        unsigned w3 = Whu[(size_t)s3 * 64 + t];
        a0 = a0 > 0.f ? a0 : 0.2f * a0;
        a1 = a1 > 0.f ? a1 : 0.2f * a1;
        a2 = a2 > 0.f ? a2 : 0.2f * a2;
        a3 = a3 > 0.f ? a3 : 0.2f * a3;
        float e0 = __expf(a0), e1 = __expf(a1), e2 = __expf(a2), e3 = __expf(a3);
        den += (e0 + e1) + (e2 + e3);
        nx = fmaf(e0, __uint_as_float(w0 << 16), nx);
        ny = fmaf(e0, __uint_as_float(w0 & 0xffff0000u), ny);
        nx = fmaf(e1, __uint_as_float(w1 << 16), nx);
        ny = fmaf(e1, __uint_as_float(w1 & 0xffff0000u), ny);
        nx = fmaf(e2, __uint_as_float(w2 << 16), nx);
        ny = fmaf(e2, __uint_as_float(w2 & 0xffff0000u), ny);
        nx = fmaf(e3, __uint_as_float(w3 << 16), nx);
        ny = fmaf(e3, __uint_as_float(w3 & 0xffff0000u), ny);
    }
    for (; j < end; ++j) {
        int s0 = rec[j];
        float a0 = s_src[s0 * N_HEADS + k] + stk;
        unsigned w0 = Whu[(size_t)s0 * 64 + t];
        a0 = a0 > 0.f ? a0 : 0.2f * a0;
        float e0 = __expf(a0);
        den += e0;
        nx = fmaf(e0, __uint_as_float(w0 << 16), nx);
        ny = fmaf(e0, __uint_as_float(w0 & 0xffff0000u), ny);
    }
    float inv = 1.f / (den + 1e-10f);
    float ox = nx * inv, oy = ny * inv;
    out[n * D_TOT + f]     = ox > 0.f ? ox : expm1f(ox);
    out[n * D_TOT + f + 1] = oy > 0.f ? oy : expm1f(oy);
}

extern "C" void kernel_launch(void* const* d_in, const int* in_sizes, int n_in,
                              void* d_out, int out_size, void* d_ws, size_t ws_size,
                              hipStream_t stream) {
    const float* x  = (const float*)d_in[0];
    const int*   ei = (const int*)d_in[1];
    const float* W  = (const float*)d_in[2];
    const float* a  = (const float*)d_in[3];
    float* out = (float*)d_out;

    const int N = in_sizes[0] / D_IN;   // 50000
    const int E = in_sizes[1] / 2;      // 1600000

    // workspace layout:
    // Whu[N*64] u32 (bf16x2) | s_src[N*4] f32 | s_tgt[N*4] f32 |
    // deg[N] i32 | row_start[N+1] | cursor[N] | rec[E]
    unsigned int* Whu = (unsigned int*)d_ws;
    float* s_src    = (float*)(Whu + (size_t)N * 64);
    float* s_tgt    = s_src + (size_t)N * N_HEADS;
    int*   deg      = (int*)(s_tgt + (size_t)N * N_HEADS);
    int*   rowstart = deg + N;
    int*   cursor   = rowstart + N + 1;
    int*   rec      = cursor + N;

    hipMemsetAsync(deg, 0, (size_t)N * sizeof(int), stream);

    const int nProj = (N + TN - 1) / TN;   // 782
    const int nDeg  = 1250;
    proj_deg_kernel<<<nProj + nDeg, 256, 0, stream>>>(
        x, W, a, ei, deg, Whu, s_src, s_tgt, N, E, nProj);

    scan_kernel<<<1, 1024, 0, stream>>>(deg, rowstart, cursor, N);
    scatter_kernel<<<(E + 255) / 256, 256, 0, stream>>>(ei, cursor, rec, E);
    agg_kernel<<<N, 64, 0, stream>>>(rec, rowstart, s_src, s_tgt, Whu, out);
}

// Round 5
// 221.639 us; speedup vs baseline: 4.4383x; 1.6640x over previous
//
#include <hip/hip_runtime.h>
#include <math.h>

#define N_HEADS 4
#define D_IN    128
#define D_OUT   32
#define D_TOT   128   // N_HEADS * D_OUT
#define TN      64    // nodes per proj block
#define XPAD    132   // padded LDS row stride (floats)
#define BSH     7     // bucket = tgt >> 7 (128 nodes/bucket)
#define BNODES  128
#define MAXNB   512   // LDS-capacity bound on bucket count (actual 391)
#define EPT     16    // edges per thread in bucketize

static __device__ __forceinline__ unsigned short f2bf(float f) {
    unsigned u = __float_as_uint(f);
    u += 0x7fffu + ((u >> 16) & 1u);
    return (unsigned short)(u >> 16);
}

// ---------------------------------------------------------------------------
// K1: proj (+ row-dots, bf16 Wh store) on blocks [0,nProj); bucket histogram
// of tgt on the rest (LDS hist -> global merge; replaces per-node degree).
// ---------------------------------------------------------------------------
__global__ __launch_bounds__(256) void proj_hist_kernel(
    const float* __restrict__ x,
    const float* __restrict__ W,
    const float* __restrict__ a,
    const int*  __restrict__ ei,
    int*  __restrict__ ghist,
    unsigned int* __restrict__ Whu,   // N x 64 uints (2 bf16 each)
    float* __restrict__ s_src,
    float* __restrict__ s_tgt,
    int N, int E, int nProj, int nb) {

    __shared__ float xs[TN][XPAD];

    if (blockIdx.x >= nProj) {
        // ---- bucket histogram over tgt ----
        int* hist = (int*)xs;
        for (int i = threadIdx.x; i < nb; i += 256) hist[i] = 0;
        __syncthreads();
        int nThreads = (gridDim.x - nProj) * 256;
        int start = (blockIdx.x - nProj) * 256 + threadIdx.x;
        for (int e = start; e < E; e += nThreads)
            atomicAdd(&hist[ei[E + e] >> BSH], 1);
        __syncthreads();
        for (int i = threadIdx.x; i < nb; i += 256)
            if (hist[i]) atomicAdd(&ghist[i], hist[i]);
        return;
    }

    const int n0 = blockIdx.x * TN;
    const int t  = threadIdx.x;

    {
        const int r  = t >> 2;
        const int c0 = (t & 3) * 32;
        int nn = n0 + r; if (nn >= N) nn = N - 1;
        const float4* src = (const float4*)(x + (size_t)nn * D_IN + c0);
        #pragma unroll
        for (int j = 0; j < 8; ++j)
            *(float4*)&xs[r][c0 + j * 4] = src[j];
    }
    __syncthreads();

    const int fg = t & 15;
    const int ng = t >> 4;
    const int f0 = fg * 8;
    const int k  = f0 >> 5;
    const int o0 = f0 & 31;
    const float* Wf = W + k * (D_IN * D_OUT) + o0;

    float acc[4][8];
    #pragma unroll
    for (int nl = 0; nl < 4; ++nl)
        #pragma unroll
        for (int j = 0; j < 8; ++j) acc[nl][j] = 0.f;

    #pragma unroll 2
    for (int i = 0; i < D_IN; i += 4) {
        float4 wa[4], wb[4];
        #pragma unroll
        for (int ii = 0; ii < 4; ++ii) {
            wa[ii] = *(const float4*)(Wf + (i + ii) * D_OUT);
            wb[ii] = *(const float4*)(Wf + (i + ii) * D_OUT + 4);
        }
        #pragma unroll
        for (int nl = 0; nl < 4; ++nl) {
            const float4 xv = *(const float4*)&xs[ng * 4 + nl][i];
            const float xr[4] = {xv.x, xv.y, xv.z, xv.w};
            #pragma unroll
            for (int ii = 0; ii < 4; ++ii) {
                acc[nl][0] = fmaf(xr[ii], wa[ii].x, acc[nl][0]);
                acc[nl][1] = fmaf(xr[ii], wa[ii].y, acc[nl][1]);
                acc[nl][2] = fmaf(xr[ii], wa[ii].z, acc[nl][2]);
                acc[nl][3] = fmaf(xr[ii], wa[ii].w, acc[nl][3]);
                acc[nl][4] = fmaf(xr[ii], wb[ii].x, acc[nl][4]);
                acc[nl][5] = fmaf(xr[ii], wb[ii].y, acc[nl][5]);
                acc[nl][6] = fmaf(xr[ii], wb[ii].z, acc[nl][6]);
                acc[nl][7] = fmaf(xr[ii], wb[ii].w, acc[nl][7]);
            }
        }
    }

    const float4 as0 = *(const float4*)(a + k * (2 * D_OUT) + o0);
    const float4 as1 = *(const float4*)(a + k * (2 * D_OUT) + o0 + 4);
    const float4 at0 = *(const float4*)(a + k * (2 * D_OUT) + D_OUT + o0);
    const float4 at1 = *(const float4*)(a + k * (2 * D_OUT) + D_OUT + o0 + 4);

    #pragma unroll
    for (int nl = 0; nl < 4; ++nl) {
        const int n = n0 + ng * 4 + nl;
        if (n < N) {
            unsigned int p[4];
            #pragma unroll
            for (int j = 0; j < 4; ++j)
                p[j] = (unsigned)f2bf(acc[nl][2 * j]) |
                       ((unsigned)f2bf(acc[nl][2 * j + 1]) << 16);
            *(uint4*)&Whu[(size_t)n * 64 + fg * 4] = make_uint4(p[0], p[1], p[2], p[3]);

            float vs = acc[nl][0] * as0.x + acc[nl][1] * as0.y +
                       acc[nl][2] * as0.z + acc[nl][3] * as0.w +
                       acc[nl][4] * as1.x + acc[nl][5] * as1.y +
                       acc[nl][6] * as1.z + acc[nl][7] * as1.w;
            float vt = acc[nl][0] * at0.x + acc[nl][1] * at0.y +
                       acc[nl][2] * at0.z + acc[nl][3] * at0.w +
                       acc[nl][4] * at1.x + acc[nl][5] * at1.y +
                       acc[nl][6] * at1.z + acc[nl][7] * at1.w;
            vs += __shfl_xor(vs, 1, 64); vs += __shfl_xor(vs, 2, 64);
            vt += __shfl_xor(vt, 1, 64); vt += __shfl_xor(vt, 2, 64);
            if ((fg & 3) == 0) {
                s_src[n * N_HEADS + k] = vs;
                s_tgt[n * N_HEADS + k] = vt;
            }
        }
    }
}

// ---------------------------------------------------------------------------
// K2: single-block exclusive scan over nb (<=512) bucket counts.
// base[0..nb] and cursor[b] = base[b].
// ---------------------------------------------------------------------------
__global__ __launch_bounds__(512) void bucket_scan_kernel(const int* __restrict__ ghist,
                                                          int* __restrict__ base,
                                                          int* __restrict__ cursor, int nb) {
    __shared__ int wsum[8];
    __shared__ int woff[8];
    const int t = threadIdx.x;
    const int lane = t & 63;
    const int wid  = t >> 6;
    int v = (t < nb) ? ghist[t] : 0;
    int incl = v;
    #pragma unroll
    for (int off = 1; off < 64; off <<= 1) {
        int tv = __shfl_up(incl, off, 64);
        if (lane >= off) incl += tv;
    }
    if (lane == 63) wsum[wid] = incl;
    __syncthreads();
    if (t == 0) {
        int c = 0;
        #pragma unroll
        for (int w = 0; w < 8; ++w) { woff[w] = c; c += wsum[w]; }
    }
    __syncthreads();
    int excl = woff[wid] + incl - v;
    if (t < nb) {
        base[t] = excl;
        cursor[t] = excl;
        if (t == nb - 1) base[nb] = excl + v;
    }
}

// ---------------------------------------------------------------------------
// K3: bucketize edges. Each block: LDS hist over its 4096 edges, ONE global
// atomic reservation per (block,bucket), then stream packed (ltgt<<16|src)
// into bucket regions. Per-block per-bucket runs are contiguous -> lines
// assembled in one XCD's L2 -> ~1.6x write amp instead of 16x.
// ---------------------------------------------------------------------------
__global__ __launch_bounds__(256) void bucketize_kernel(const int* __restrict__ ei,
                                                        int* __restrict__ cursor,
                                                        unsigned int* __restrict__ bbuf,
                                                        int E, int nb) {
    __shared__ int cnt[MAXNB];
    const int t = threadIdx.x;
    for (int i = t; i < nb; i += 256) cnt[i] = 0;
    __syncthreads();

    const int e0 = blockIdx.x * (256 * EPT);
    int src[EPT], tgt[EPT];
    #pragma unroll
    for (int i = 0; i < EPT; ++i) {
        int e = e0 + i * 256 + t;
        if (e < E) {
            src[i] = ei[e];
            tgt[i] = ei[E + e];
            atomicAdd(&cnt[tgt[i] >> BSH], 1);
        } else {
            src[i] = -1; tgt[i] = 0;
        }
    }
    __syncthreads();
    for (int b = t; b < nb; b += 256)
        if (cnt[b]) cnt[b] = atomicAdd(&cursor[b], cnt[b]);
    __syncthreads();
    #pragma unroll
    for (int i = 0; i < EPT; ++i) {
        if (src[i] >= 0) {
            int b = tgt[i] >> BSH;
            int pos = atomicAdd(&cnt[b], 1);
            bbuf[pos] = ((unsigned)(tgt[i] & (BNODES - 1)) << 16) | (unsigned)src[i];
        }
    }
}

// ---------------------------------------------------------------------------
// K4: per-bucket finalize. LDS per-node degree -> scan -> row_start, then
// scatter src into rec (writes confined to this bucket's ~16KB window).
// ---------------------------------------------------------------------------
__global__ __launch_bounds__(256) void finalize_kernel(const unsigned int* __restrict__ bbuf,
                                                       const int* __restrict__ base,
                                                       int* __restrict__ row_start,
                                                       int* __restrict__ rec,
                                                       int N, int E) {
    __shared__ int deg[BNODES];
    __shared__ int cur[BNODES];
    __shared__ int wsum2[2];
    const int b = blockIdx.x;
    const int t = threadIdx.x;
    const int beg = base[b];
    const int fin = base[b + 1];

    if (t < BNODES) deg[t] = 0;
    __syncthreads();
    for (int j = beg + t; j < fin; j += 256)
        atomicAdd(&deg[bbuf[j] >> 16], 1);
    __syncthreads();

    if (t < BNODES) {
        const int lane = t & 63;
        const int wid  = t >> 6;     // 0 or 1
        int v = deg[t];
        int incl = v;
        #pragma unroll
        for (int off = 1; off < 64; off <<= 1) {
            int tv = __shfl_up(incl, off, 64);
            if (lane >= off) incl += tv;
        }
        if (lane == 63) wsum2[wid] = incl;
        __syncthreads();
        int excl = incl - v + (wid ? wsum2[0] : 0);
        cur[t] = beg + excl;
        int n = b * BNODES + t;
        if (n <= N) row_start[n] = beg + excl;
    } else {
        __syncthreads();
    }
    __syncthreads();

    for (int j = beg + t; j < fin; j += 256) {
        unsigned v = bbuf[j];
        int pos = atomicAdd(&cur[v >> 16], 1);
        rec[pos] = (int)(v & 0xFFFFu);
    }
}

// ---------------------------------------------------------------------------
// K5: aggregate (unchanged): one wave per target node; packed-bf16 Wh gather,
// register softmax accumulation, single f32 write with ELU fused.
// ---------------------------------------------------------------------------
__global__ __launch_bounds__(64) void agg_kernel(const int* __restrict__ rec,
                                                 const int* __restrict__ row_start,
                                                 const float* __restrict__ s_src,
                                                 const float* __restrict__ s_tgt,
                                                 const unsigned int* __restrict__ Whu,
                                                 float* __restrict__ out) {
    const int n = blockIdx.x;
    const int t = threadIdx.x;
    const int f = t * 2;
    const int k = f >> 5;
    const int beg = row_start[n];
    const int end = row_start[n + 1];
    const float stk = s_tgt[n * N_HEADS + k];

    float den = 0.f;
    float nx = 0.f, ny = 0.f;
    int j = beg;
    for (; j + 4 <= end; j += 4) {
        int s0 = rec[j], s1 = rec[j + 1], s2 = rec[j + 2], s3 = rec[j + 3];
        float a0 = s_src[s0 * N_HEADS + k] + stk;
        float a1 = s_src[s1 * N_HEADS + k] + stk;
        float a2 = s_src[s2 * N_HEADS + k] + stk;
        float a3 = s_src[s3 * N_HEADS + k] + stk;
        unsigned w0 = Whu[(size_t)s0 * 64 + t];
        unsigned w1 = Whu[(size_t)s1 * 64 + t];
        unsigned w2 = Whu[(size_t)s2 * 64 + t];
        unsigned w3 = Whu[(size_t)s3 * 64 + t];
        a0 = a0 > 0.f ? a0 : 0.2f * a0;
        a1 = a1 > 0.f ? a1 : 0.2f * a1;
        a2 = a2 > 0.f ? a2 : 0.2f * a2;
        a3 = a3 > 0.f ? a3 : 0.2f * a3;
        float e0 = __expf(a0), e1 = __expf(a1), e2 = __expf(a2), e3 = __expf(a3);
        den += (e0 + e1) + (e2 + e3);
        nx = fmaf(e0, __uint_as_float(w0 << 16), nx);
        ny = fmaf(e0, __uint_as_float(w0 & 0xffff0000u), ny);
        nx = fmaf(e1, __uint_as_float(w1 << 16), nx);
        ny = fmaf(e1, __uint_as_float(w1 & 0xffff0000u), ny);
        nx = fmaf(e2, __uint_as_float(w2 << 16), nx);
        ny = fmaf(e2, __uint_as_float(w2 & 0xffff0000u), ny);
        nx = fmaf(e3, __uint_as_float(w3 << 16), nx);
        ny = fmaf(e3, __uint_as_float(w3 & 0xffff0000u), ny);
    }
    for (; j < end; ++j) {
        int s0 = rec[j];
        float a0 = s_src[s0 * N_HEADS + k] + stk;
        unsigned w0 = Whu[(size_t)s0 * 64 + t];
        a0 = a0 > 0.f ? a0 : 0.2f * a0;
        float e0 = __expf(a0);
        den += e0;
        nx = fmaf(e0, __uint_as_float(w0 << 16), nx);
        ny = fmaf(e0, __uint_as_float(w0 & 0xffff0000u), ny);
    }
    float inv = 1.f / (den + 1e-10f);
    float ox = nx * inv, oy = ny * inv;
    out[n * D_TOT + f]     = ox > 0.f ? ox : expm1f(ox);
    out[n * D_TOT + f + 1] = oy > 0.f ? oy : expm1f(oy);
}

extern "C" void kernel_launch(void* const* d_in, const int* in_sizes, int n_in,
                              void* d_out, int out_size, void* d_ws, size_t ws_size,
                              hipStream_t stream) {
    const float* x  = (const float*)d_in[0];
    const int*   ei = (const int*)d_in[1];
    const float* W  = (const float*)d_in[2];
    const float* a  = (const float*)d_in[3];
    float* out = (float*)d_out;

    const int N = in_sizes[0] / D_IN;   // 50000
    const int E = in_sizes[1] / 2;      // 1600000
    const int nb = (N + BNODES - 1) >> BSH;   // 391

    // workspace layout:
    // Whu[N*64] u32 | s_src[N*4] f32 | s_tgt[N*4] f32 |
    // ghist[nb] | base[nb+1] | cursor[nb] | row_start[N+1] | bbuf[E] u32 | rec[E]
    unsigned int* Whu = (unsigned int*)d_ws;
    float* s_src    = (float*)(Whu + (size_t)N * 64);
    float* s_tgt    = s_src + (size_t)N * N_HEADS;
    int*   ghist    = (int*)(s_tgt + (size_t)N * N_HEADS);
    int*   base     = ghist + nb;
    int*   cursor   = base + nb + 1;
    int*   rowstart = cursor + nb;
    unsigned int* bbuf = (unsigned int*)(rowstart + N + 1);
    int*   rec      = (int*)(bbuf + E);

    hipMemsetAsync(ghist, 0, (size_t)nb * sizeof(int), stream);

    const int nProj = (N + TN - 1) / TN;   // 782
    const int nHist = 256;
    proj_hist_kernel<<<nProj + nHist, 256, 0, stream>>>(
        x, W, a, ei, ghist, Whu, s_src, s_tgt, N, E, nProj, nb);

    bucket_scan_kernel<<<1, 512, 0, stream>>>(ghist, base, cursor, nb);

    const int nBkt = (E + 256 * EPT - 1) / (256 * EPT);   // 391
    bucketize_kernel<<<nBkt, 256, 0, stream>>>(ei, cursor, bbuf, E, nb);

    finalize_kernel<<<nb, 256, 0, stream>>>(bbuf, base, rowstart, rec, N, E);

    agg_kernel<<<N, 64, 0, stream>>>(rec, rowstart, s_src, s_tgt, Whu, out);
}